// Round 3
// baseline (1752.770 us; speedup 1.0000x reference)
//
#include <hip/hip_runtime.h>

using uint = unsigned int;
using u16  = unsigned short;
using ll   = long long;

constexpr int cL = 4, cH = 12, cDH = 64, cD = 768, cM = 3072, cV = 32000, cS = 1024, cB = 2;
constexpr int cT  = cB * cS;   // 2048 tokens
constexpr int cBH = cB * cH;   // 24

using bf16x8 = __bf16 __attribute__((ext_vector_type(8)));
using f32x4  = float  __attribute__((ext_vector_type(4)));

__device__ __forceinline__ float b2f(u16 u) {
    union { uint i; float f; } v; v.i = ((uint)u) << 16; return v.f;
}
__device__ __forceinline__ u16 f2b(float f) {
    union { float f; uint i; } v; v.f = f;
    uint u = v.i;
    return (u16)((u + 0x7fffu + ((u >> 16) & 1u)) >> 16);   // RNE
}
// read input element `idx` as float, per mode (1 = bf16, 0 = f32)
__device__ __forceinline__ float inp(const void* p, ll idx, int md) {
    return md ? b2f(((const u16*)p)[idx]) : ((const float*)p)[idx];
}
__device__ __forceinline__ float wave_sum(float v) {
    #pragma unroll
    for (int m = 32; m; m >>= 1) v += __shfl_xor(v, m);
    return v;
}
__device__ __forceinline__ float wave_max(float v) {
    #pragma unroll
    for (int m = 32; m; m >>= 1) v = fmaxf(v, __shfl_xor(v, m));
    return v;
}
__device__ __forceinline__ void gload16(const u16* g, u16* l) {
    __builtin_amdgcn_global_load_lds(
        (const __attribute__((address_space(1))) uint*)g,
        (__attribute__((address_space(3))) uint*)l,
        16, 0, 0);
}

// ---------------- dtype detector ------------------------------------------------------
__global__ void detect_k(const uint* __restrict__ e, int* __restrict__ flag)
{
    const int l = threadIdx.x;
    int hits = 0;
    #pragma unroll
    for (int i = 0; i < 4; ++i) {
        uint w  = e[l * 4 + i];
        uint ex = (w >> 7) & 0xffu;          // bf16-pair: low element's exponent field
        hits += (ex >= 100u && ex <= 126u) ? 1 : 0;
    }
    float s = wave_sum((float)hits);
    if (l == 0) *flag = (s >= 128.f) ? 1 : 0;   // 1 = bf16 inputs, 0 = f32 inputs
}

// ---------------- GEMM: C = A[M,K] * Bt[N,K]^T (A,Bt bf16 internal buffers) ----------
// OUTK: 0 = f32 store, 1 = bf16 store, 2 = dynamic (md ? bf16 : f32)
template<int BM, int BN, int WGM, int WGN, int OUTK, bool GELU>
__global__ __launch_bounds__(256)
void gemm_bt(const u16* __restrict__ A, int lda, ll offAo, ll offAi,
             const u16* __restrict__ Bt, int ldb, ll offBo, ll offBi,
             void* __restrict__ Cv, int ldc, ll offCo, ll offCi,
             int HB, int K,
             const void* __restrict__ bias, ll bias_off, float scale,
             const float* __restrict__ r1, const float* __restrict__ r2,
             const int* __restrict__ modeflag)
{
    constexpr int MF = BM / WGM / 16;
    constexpr int NF = BN / WGN / 16;
    static_assert(BM % (WGM * 16) == 0 && BN % (WGN * 16) == 0, "tile/wave mismatch");
    static_assert(WGM * WGN == 4, "4 waves");
    __shared__ __align__(16) u16 sA[BM * 64];
    __shared__ __align__(16) u16 sB[BN * 64];

    const int md = *modeflag;
    const int z = blockIdx.z;
    const ll zo = z / HB, zi = z % HB;
    const u16* Ab = A + zo * offAo + zi * offAi;
    const u16* Bb = Bt + zo * offBo + zi * offBi;

    const int tid  = threadIdx.x;
    const int lane = tid & 63, wid = tid >> 6;
    const int wr = wid / WGN, wc = wid % WGN;
    const int rowTile = blockIdx.y * BM, colTile = blockIdx.x * BN;
    const int lr = lane >> 3, lc8 = (lane & 7) << 3;

    f32x4 zero = {0.f, 0.f, 0.f, 0.f};
    f32x4 acc[MF][NF];
    #pragma unroll
    for (int m = 0; m < MF; ++m)
        #pragma unroll
        for (int n = 0; n < NF; ++n) acc[m][n] = zero;

    const int nkt = K >> 6;
    for (int kt = 0; kt < nkt; ++kt) {
        const int k0 = kt << 6;
        #pragma unroll
        for (int i = 0; i < BM / 32; ++i) {
            int c = i * 4 + wid;
            gload16(Ab + (size_t)(rowTile + c * 8 + lr) * lda + k0 + lc8, &sA[c * 512]);
        }
        #pragma unroll
        for (int i = 0; i < BN / 32; ++i) {
            int c = i * 4 + wid;
            gload16(Bb + (size_t)(colTile + c * 8 + lr) * ldb + k0 + lc8, &sB[c * 512]);
        }
        asm volatile("s_waitcnt vmcnt(0)" ::: "memory");
        __syncthreads();
        #pragma unroll
        for (int kk = 0; kk < 2; ++kk) {
            const int ko = kk * 32 + (lane >> 4) * 8;
            bf16x8 af[MF], bfv[NF];
            #pragma unroll
            for (int m = 0; m < MF; ++m)
                af[m] = *(const bf16x8*)&sA[(wr * (BM / WGM) + m * 16 + (lane & 15)) * 64 + ko];
            #pragma unroll
            for (int n = 0; n < NF; ++n)
                bfv[n] = *(const bf16x8*)&sB[(wc * (BN / WGN) + n * 16 + (lane & 15)) * 64 + ko];
            #pragma unroll
            for (int m = 0; m < MF; ++m)
                #pragma unroll
                for (int n = 0; n < NF; ++n)
                    acc[m][n] = __builtin_amdgcn_mfma_f32_16x16x32_bf16(af[m], bfv[n], acc[m][n], 0, 0, 0);
        }
        __syncthreads();
    }

    const ll offC = zo * offCo + zi * offCi;
    #pragma unroll
    for (int m = 0; m < MF; ++m) {
        #pragma unroll
        for (int n = 0; n < NF; ++n) {
            const int col = colTile + wc * (BN / WGN) + n * 16 + (lane & 15);
            const float bv = bias ? inp(bias, bias_off + col, md) : 0.f;
            #pragma unroll
            for (int r = 0; r < 4; ++r) {
                const int row = rowTile + wr * (BM / WGM) + m * 16 + ((lane >> 4) << 2) + r;
                float xv = acc[m][n][r] * scale + bv;
                if constexpr (GELU) xv = 0.5f * xv * (1.f + erff(xv * 0.70710678118654752f));
                const size_t idx = (size_t)row * ldc + col;
                if (r1) xv += r1[idx];
                if (r2) xv += r2[idx];
                if constexpr (OUTK == 1)      ((u16*)Cv)[offC + idx] = f2b(xv);
                else if constexpr (OUTK == 0) ((float*)Cv)[offC + idx] = xv;
                else {
                    if (md) ((u16*)Cv)[offC + idx] = f2b(xv);
                    else    ((float*)Cv)[offC + idx] = xv;
                }
            }
        }
    }
}

// ------- transpose input weight (bf16 OR f32) -> bf16: out[z*oS + c*outs + r] --------
__global__ __launch_bounds__(256)
void transpose_k(const void* __restrict__ in, u16* __restrict__ out,
                 int R, int C, int ins, int outs,
                 ll base, ll iStride, ll oStride,
                 const int* __restrict__ modeflag)
{
    __shared__ u16 tile[32][33];
    const int md = *modeflag;
    const int z = blockIdx.z;
    const ll ioff = base + (ll)z * iStride;
    u16* op = out + (ll)z * oStride;
    const int tx = threadIdx.x & 31, ty = threadIdx.x >> 5;
    const int c0 = blockIdx.x * 32, r0 = blockIdx.y * 32;
    #pragma unroll
    for (int i = 0; i < 32; i += 8) {
        int r = r0 + ty + i, c = c0 + tx;
        if (r < R && c < C) tile[ty + i][tx] = f2b(inp(in, ioff + (ll)r * ins + c, md));
    }
    __syncthreads();
    #pragma unroll
    for (int i = 0; i < 32; i += 8) {
        int c = c0 + ty + i, r = r0 + tx;
        if (c < C && r < R) op[(size_t)c * outs + r] = tile[tx][ty + i];
    }
}

// ---- bf16-input fast transpose for internal V buffer (always bf16) -------------------
__global__ __launch_bounds__(256)
void transpose_b_k(const u16* __restrict__ in, u16* __restrict__ out,
                   int R, int C, int ins, int outs,
                   ll iOo, ll iOi, ll oOo, ll oOi, int HB)
{
    __shared__ u16 tile[32][33];
    const int z = blockIdx.z;
    const u16* ip = in  + (ll)(z / HB) * iOo + (ll)(z % HB) * iOi;
    u16*       op = out + (ll)(z / HB) * oOo + (ll)(z % HB) * oOi;
    const int tx = threadIdx.x & 31, ty = threadIdx.x >> 5;
    const int c0 = blockIdx.x * 32, r0 = blockIdx.y * 32;
    #pragma unroll
    for (int i = 0; i < 32; i += 8) {
        int r = r0 + ty + i, c = c0 + tx;
        if (r < R && c < C) tile[ty + i][tx] = ip[(size_t)r * ins + c];
    }
    __syncthreads();
    #pragma unroll
    for (int i = 0; i < 32; i += 8) {
        int c = c0 + ty + i, r = r0 + tx;
        if (c < C && r < R) op[(size_t)c * outs + r] = tile[tx][ty + i];
    }
}

// ---------------- embedding: res = E[x] + P (f32 out) --------------------------------
__global__ __launch_bounds__(192)
void embed_k(const int* __restrict__ x, const void* __restrict__ E,
             const void* __restrict__ P, float* __restrict__ res,
             const int* __restrict__ modeflag)
{
    const int md = *modeflag;
    const int tok = blockIdx.x, t = threadIdx.x;
    const int s = tok & (cS - 1);
    const ll  eb = (ll)x[tok] * cD, pb = (ll)s * cD;
    float4 o;
    o.x = inp(E, eb + t * 4 + 0, md) + inp(P, pb + t * 4 + 0, md);
    o.y = inp(E, eb + t * 4 + 1, md) + inp(P, pb + t * 4 + 1, md);
    o.z = inp(E, eb + t * 4 + 2, md) + inp(P, pb + t * 4 + 2, md);
    o.w = inp(E, eb + t * 4 + 3, md) + inp(P, pb + t * 4 + 3, md);
    ((float4*)(res + (size_t)tok * cD))[t] = o;
}

// ---------------- layernorm (unbiased std, ddof=1), f32 in, bf16 out ------------------
__global__ __launch_bounds__(192)
void ln_k(const float* __restrict__ in, const void* __restrict__ w,
          const void* __restrict__ b, ll wb_off, u16* __restrict__ out,
          const int* __restrict__ modeflag)
{
    __shared__ float sm[8];
    const int md = *modeflag;
    const int row = blockIdx.x, t = threadIdx.x;
    const float4 x = ((const float4*)(in + (size_t)row * cD))[t];
    float s = wave_sum(x.x + x.y + x.z + x.w);
    const int lane = t & 63, wv = t >> 6;
    if (!lane) sm[wv] = s;
    __syncthreads();
    const float mu = (sm[0] + sm[1] + sm[2]) * (1.f / (float)cD);
    const float dx = x.x - mu, dy = x.y - mu, dz = x.z - mu, dw = x.w - mu;
    float ss = wave_sum(dx * dx + dy * dy + dz * dz + dw * dw);
    if (!lane) sm[4 + wv] = ss;
    __syncthreads();
    const float var = (sm[4] + sm[5] + sm[6]) * (1.f / (float)(cD - 1));
    const float rs  = 1.f / sqrtf(var);
    const ll o4 = wb_off + (ll)t * 4;
    ushort4 o;
    o.x = f2b(inp(w, o4 + 0, md) * (dx * rs) + inp(b, o4 + 0, md));
    o.y = f2b(inp(w, o4 + 1, md) * (dy * rs) + inp(b, o4 + 1, md));
    o.z = f2b(inp(w, o4 + 2, md) * (dz * rs) + inp(b, o4 + 2, md));
    o.w = f2b(inp(w, o4 + 3, md) * (dw * rs) + inp(b, o4 + 3, md));
    ((ushort4*)(out + (size_t)row * cD))[t] = o;
}

// ---------------- causal softmax, in-place on bf16 [rows=BH*S][S] ---------------------
__global__ __launch_bounds__(256)
void softmax_k(u16* __restrict__ p)
{
    __shared__ float sm[8];
    const int row = blockIdx.x;
    const int q = row & (cS - 1);
    u16* pr = p + (size_t)row * cS;
    const int t = threadIdx.x;
    ushort4 v = ((const ushort4*)pr)[t];
    const int j0 = t * 4;
    float x0 = (j0 + 0 <= q) ? b2f(v.x) : -100000.f;
    float x1 = (j0 + 1 <= q) ? b2f(v.y) : -100000.f;
    float x2 = (j0 + 2 <= q) ? b2f(v.z) : -100000.f;
    float x3 = (j0 + 3 <= q) ? b2f(v.w) : -100000.f;
    float mx = wave_max(fmaxf(fmaxf(x0, x1), fmaxf(x2, x3)));
    const int lane = t & 63, wv = t >> 6;
    if (!lane) sm[wv] = mx;
    __syncthreads();
    const float MX = fmaxf(fmaxf(sm[0], sm[1]), fmaxf(sm[2], sm[3]));
    const float e0 = expf(x0 - MX), e1 = expf(x1 - MX), e2 = expf(x2 - MX), e3 = expf(x3 - MX);
    float ssum = wave_sum(e0 + e1 + e2 + e3);
    if (!lane) sm[4 + wv] = ssum;
    __syncthreads();
    const float inv = 1.f / (sm[4] + sm[5] + sm[6] + sm[7]);
    ushort4 o;
    o.x = f2b(e0 * inv); o.y = f2b(e1 * inv); o.z = f2b(e2 * inv); o.w = f2b(e3 * inv);
    ((ushort4*)pr)[t] = o;
}

// =====================================================================================
extern "C" void kernel_launch(void* const* d_in, const int* in_sizes, int n_in,
                              void* d_out, int out_size, void* d_ws, size_t ws_size,
                              hipStream_t stream)
{
    (void)in_sizes; (void)n_in; (void)out_size;
    const int*  x     = (const int*)d_in[0];
    const void* E_w   = d_in[1];
    const void* P_w   = d_in[2];
    const void* ln1_w = d_in[3];
    const void* ln1_b = d_in[4];
    const void* Q_w   = d_in[5];
    const void* Q_b   = d_in[6];
    const void* K_w   = d_in[7];
    const void* K_b   = d_in[8];
    const void* V_w   = d_in[9];
    const void* V_b   = d_in[10];
    const void* O_w   = d_in[11];
    const void* O_b   = d_in[12];
    const void* ln2_w = d_in[13];
    const void* ln2_b = d_in[14];
    const void* In_w  = d_in[15];
    const void* In_b  = d_in[16];
    const void* Out_w = d_in[17];
    const void* Out_b = d_in[18];
    const void* lnf_w = d_in[19];
    const void* lnf_b = d_in[20];
    const void* U_w   = d_in[21];
    const void* U_b   = d_in[22];

    // ---- workspace carve with aliasing (~97 MB) ----
    char* wp = (char*)d_ws;
    auto carve = [&](size_t bytes) { char* r = wp; wp += (bytes + 255) & ~(size_t)255; return r; };
    int*   modeflag = (int*)carve(256);
    float* res   = (float*)carve((size_t)cT * cD * 4);
    float* resat = (float*)carve((size_t)cT * cD * 4);
    u16* h     = (u16*)carve((size_t)cT * cD * 2);
    u16* attnb = (u16*)carve((size_t)cT * cD * 2);
    u16* qb    = (u16*)carve((size_t)cT * cD * 2 * 4);   // q/k/v/vt block
    u16* kb    = qb + (size_t)cT * cD;
    u16* vb    = kb + (size_t)cT * cD;
    u16* vt    = vb + (size_t)cT * cD;
    u16* mlpb  = qb;                                     // alias (disjoint lifetime)
    u16* WqT   = (u16*)carve((size_t)cD * cD * 2);
    u16* WkT   = (u16*)carve((size_t)cD * cD * 2);
    u16* WvT   = (u16*)carve((size_t)cD * cD * 2);
    u16* WoT   = (u16*)carve((size_t)cD * cD * 2);
    u16* WinT  = (u16*)carve((size_t)cD * cM * 2);
    u16* WoutT = (u16*)carve((size_t)cD * cM * 2);
    u16* pbuf  = (u16*)carve((size_t)cBH * cS * cS * 2);
    u16* WuT   = pbuf;                                   // alias (pbuf dead after layers)

    if (ws_size && (size_t)(wp - (char*)d_ws) > ws_size) return;  // tripwire

    detect_k<<<1, 64, 0, stream>>>((const uint*)E_w, modeflag);
    embed_k<<<cT, 192, 0, stream>>>(x, E_w, P_w, res, modeflag);

    for (int l = 0; l < cL; ++l) {
        const ll wqkv = (ll)l * cH * cD * cDH;
        // per-layer weight transposes (convert f32->bf16 if needed, inside)
        transpose_k<<<dim3(2, 24, cH), 256, 0, stream>>>(
            Q_w, WqT, cD, cDH, cDH, cD, wqkv, (ll)cD * cDH, (ll)cDH * cD, modeflag);
        transpose_k<<<dim3(2, 24, cH), 256, 0, stream>>>(
            K_w, WkT, cD, cDH, cDH, cD, wqkv, (ll)cD * cDH, (ll)cDH * cD, modeflag);
        transpose_k<<<dim3(2, 24, cH), 256, 0, stream>>>(
            V_w, WvT, cD, cDH, cDH, cD, wqkv, (ll)cD * cDH, (ll)cDH * cD, modeflag);
        transpose_k<<<dim3(24, 24, 1), 256, 0, stream>>>(
            O_w, WoT, cD, cD, cD, cD, (ll)l * cD * cD, 0, 0, modeflag);
        transpose_k<<<dim3(cM / 32, 24, 1), 256, 0, stream>>>(
            In_w, WinT, cD, cM, cM, cD, (ll)l * cD * cM, 0, 0, modeflag);
        transpose_k<<<dim3(24, cM / 32, 1), 256, 0, stream>>>(
            Out_w, WoutT, cM, cD, cD, cM, (ll)l * cM * cD, 0, 0, modeflag);

        // LN1
        ln_k<<<cT, 192, 0, stream>>>(res, ln1_w, ln1_b, (ll)l * cD, h, modeflag);

        // Q, K, V projections (M=2048, N=768, K=768)
        gemm_bt<128, 128, 2, 2, 1, false><<<dim3(6, 16, 1), 256, 0, stream>>>(
            h, cD, 0, 0, WqT, cD, 0, 0, qb, cD, 0, 0, 1, cD,
            Q_b, (ll)l * cH * cDH, 1.f, nullptr, nullptr, modeflag);
        gemm_bt<128, 128, 2, 2, 1, false><<<dim3(6, 16, 1), 256, 0, stream>>>(
            h, cD, 0, 0, WkT, cD, 0, 0, kb, cD, 0, 0, 1, cD,
            K_b, (ll)l * cH * cDH, 1.f, nullptr, nullptr, modeflag);
        gemm_bt<128, 128, 2, 2, 1, false><<<dim3(6, 16, 1), 256, 0, stream>>>(
            h, cD, 0, 0, WvT, cD, 0, 0, vb, cD, 0, 0, 1, cD,
            V_b, (ll)l * cH * cDH, 1.f, nullptr, nullptr, modeflag);

        // V -> Vt [B,H,DH,S]
        transpose_b_k<<<dim3(2, cS / 32, cBH), 256, 0, stream>>>(
            vb, vt, cS, cDH, cH * cDH, cS,
            (ll)cS * cH * cDH, cDH, (ll)cH * cDH * cS, (ll)cDH * cS, cH);

        // logits = Q K^T * 1/8, batched over (b,h)
        gemm_bt<128, 128, 2, 2, 1, false><<<dim3(8, 8, cBH), 256, 0, stream>>>(
            qb, cD, (ll)cS * cD, cDH,
            kb, cD, (ll)cS * cD, cDH,
            pbuf, cS, (ll)cH * cS * cS, (ll)cS * cS,
            cH, cDH, nullptr, 0, 0.125f, nullptr, nullptr, modeflag);

        softmax_k<<<cBH * cS, 256, 0, stream>>>(pbuf);

        // attn = P V, batched
        gemm_bt<128, 64, 4, 1, 1, false><<<dim3(1, 8, cBH), 256, 0, stream>>>(
            pbuf, cS, (ll)cH * cS * cS, (ll)cS * cS,
            vt, cS, (ll)cH * cDH * cS, (ll)cDH * cS,
            attnb, cD, (ll)cS * cD, cDH,
            cH, cS, nullptr, 0, 1.f, nullptr, nullptr, modeflag);

        // O projection + residual -> resat (f32)
        gemm_bt<128, 128, 2, 2, 0, false><<<dim3(6, 16, 1), 256, 0, stream>>>(
            attnb, cD, 0, 0, WoT, cD, 0, 0, resat, cD, 0, 0, 1, cD,
            O_b, (ll)l * cD, 1.f, res, nullptr, modeflag);

        // LN2
        ln_k<<<cT, 192, 0, stream>>>(resat, ln2_w, ln2_b, (ll)l * cD, h, modeflag);

        // MLP in: gelu(h @ Win + bIn)
        gemm_bt<128, 128, 2, 2, 1, true><<<dim3(cM / 128, 16, 1), 256, 0, stream>>>(
            h, cD, 0, 0, WinT, cD, 0, 0, mlpb, cM, 0, 0, 1, cD,
            In_b, (ll)l * cM, 1.f, nullptr, nullptr, modeflag);

        // MLP out + double residual: res = res + resat + (m @ Wout + bOut)
        gemm_bt<128, 128, 2, 2, 0, false><<<dim3(6, 16, 1), 256, 0, stream>>>(
            mlpb, cM, 0, 0, WoutT, cM, 0, 0, res, cD, 0, 0, 1, cM,
            Out_b, (ll)l * cD, 1.f, res, resat, modeflag);
    }

    // unembed weight transpose (WuT aliases pbuf), final LN, unembed (dynamic out dtype)
    transpose_k<<<dim3(cV / 32, cD / 32, 1), 256, 0, stream>>>(
        U_w, WuT, cD, cV, cV, cD, 0, 0, 0, modeflag);
    ln_k<<<cT, 192, 0, stream>>>(res, lnf_w, lnf_b, 0, h, modeflag);
    gemm_bt<128, 128, 2, 2, 2, false><<<dim3(cV / 128, 16, 1), 256, 0, stream>>>(
        h, cD, 0, 0, WuT, cD, 0, 0, d_out, cV, 0, 0, 1, cD,
        U_b, 0, 1.f, nullptr, nullptr, modeflag);
}

// Round 4
// 1557.386 us; speedup vs baseline: 1.1255x; 1.1255x over previous
//
#include <hip/hip_runtime.h>

using uint = unsigned int;
using u16  = unsigned short;
using ll   = long long;

constexpr int cL = 4, cH = 12, cDH = 64, cD = 768, cM = 3072, cV = 32000, cS = 1024, cB = 2;
constexpr int cT  = cB * cS;   // 2048 tokens
constexpr int cBH = cB * cH;   // 24
constexpr int cQKV = 3 * cD;   // 2304

using bf16x8 = __bf16 __attribute__((ext_vector_type(8)));
using f32x4  = float  __attribute__((ext_vector_type(4)));

__device__ __forceinline__ float b2f(u16 u) {
    union { uint i; float f; } v; v.i = ((uint)u) << 16; return v.f;
}
__device__ __forceinline__ u16 f2b(float f) {
    union { float f; uint i; } v; v.f = f;
    uint u = v.i;
    return (u16)((u + 0x7fffu + ((u >> 16) & 1u)) >> 16);   // RNE
}
// read input element `idx` as float, per mode (1 = bf16, 0 = f32)
__device__ __forceinline__ float inp(const void* p, ll idx, int md) {
    return md ? b2f(((const u16*)p)[idx]) : ((const float*)p)[idx];
}
__device__ __forceinline__ float wave_sum(float v) {
    #pragma unroll
    for (int m = 32; m; m >>= 1) v += __shfl_xor(v, m);
    return v;
}
__device__ __forceinline__ float wave_max(float v) {
    #pragma unroll
    for (int m = 32; m; m >>= 1) v = fmaxf(v, __shfl_xor(v, m));
    return v;
}
__device__ __forceinline__ void gload16(const u16* g, u16* l) {
    __builtin_amdgcn_global_load_lds(
        (const __attribute__((address_space(1))) uint*)g,
        (__attribute__((address_space(3))) uint*)l,
        16, 0, 0);
}

// ---------------- dtype detector ------------------------------------------------------
__global__ void detect_k(const uint* __restrict__ e, int* __restrict__ flag)
{
    const int l = threadIdx.x;
    int hits = 0;
    #pragma unroll
    for (int i = 0; i < 4; ++i) {
        uint w  = e[l * 4 + i];
        uint ex = (w >> 7) & 0xffu;
        hits += (ex >= 100u && ex <= 126u) ? 1 : 0;
    }
    float s = wave_sum((float)hits);
    if (l == 0) *flag = (s >= 128.f) ? 1 : 0;   // 1 = bf16 inputs, 0 = f32 inputs
}

// ---------------- pack QKV biases -> f32 [L][2304] ------------------------------------
__global__ __launch_bounds__(256)
void packbias_k(const void* __restrict__ Qb, const void* __restrict__ Kb,
                const void* __restrict__ Vb, float* __restrict__ out,
                const int* __restrict__ modeflag)
{
    const int md = *modeflag;
    const int i = blockIdx.x * 256 + threadIdx.x;   // i < L*2304
    const int l = i / cQKV, c = i % cQKV;
    float v;
    if (c < cD)           v = inp(Qb, (ll)l * cD + c, md);
    else if (c < 2 * cD)  v = inp(Kb, (ll)l * cD + c - cD, md);
    else                  v = inp(Vb, (ll)l * cD + c - 2 * cD, md);
    out[i] = v;
}

// ---------------- GEMM: C = A[M,K] * Bt[N,K]^T (A,Bt bf16 internal buffers) -----------
// OUTK: 0=f32 store, 1=bf16 store, 2=dynamic (md?bf16:f32)
// COLMAJ: rowTile from blockIdx.x (consecutive blocks share B col-panel)
// CSKIP: causal QK^T — skip tiles entirely in the future
// CK:    causal PV   — K-loop limited to rowTile+BM
// BIASK: 0=none, 1=input-dtype bias, 2=f32 bias
template<int BM, int BN, int WGM, int WGN, int OUTK, bool GELU,
         bool COLMAJ, bool CSKIP, bool CK, int BIASK>
__global__ __launch_bounds__(256)
void gemm_bt(const u16* __restrict__ A, int lda, ll offAo, ll offAi,
             const u16* __restrict__ Bt, int ldb, ll offBo, ll offBi,
             void* __restrict__ Cv, int ldc, ll offCo, ll offCi,
             int HB, int K,
             const void* __restrict__ bias, ll bias_off, float scale,
             const float* __restrict__ r1, const float* __restrict__ r2,
             const int* __restrict__ modeflag)
{
    constexpr int MF = BM / WGM / 16;
    constexpr int NF = BN / WGN / 16;
    static_assert(BM % (WGM * 16) == 0 && BN % (WGN * 16) == 0, "tile/wave mismatch");
    static_assert(WGM * WGN == 4, "4 waves");
    __shared__ __align__(16) u16 sA[BM * 64];
    __shared__ __align__(16) u16 sB[BN * 64];

    const int rowTile = (COLMAJ ? blockIdx.x : blockIdx.y) * BM;
    const int colTile = (COLMAJ ? blockIdx.y : blockIdx.x) * BN;
    if constexpr (CSKIP) {
        if (colTile >= rowTile + BM) return;   // strictly-future tile
    }

    const int md = *modeflag;
    const int z = blockIdx.z;
    const ll zo = z / HB, zi = z % HB;
    const u16* Ab = A + zo * offAo + zi * offAi;
    const u16* Bb = Bt + zo * offBo + zi * offBi;

    const int tid  = threadIdx.x;
    const int lane = tid & 63, wid = tid >> 6;
    const int wr = wid / WGN, wc = wid % WGN;
    const int lr = lane >> 3, lc8 = (lane & 7) << 3;

    f32x4 zero = {0.f, 0.f, 0.f, 0.f};
    f32x4 acc[MF][NF];
    #pragma unroll
    for (int m = 0; m < MF; ++m)
        #pragma unroll
        for (int n = 0; n < NF; ++n) acc[m][n] = zero;

    const int nkt = CK ? ((rowTile + BM) >> 6) : (K >> 6);
    for (int kt = 0; kt < nkt; ++kt) {
        const int k0 = kt << 6;
        #pragma unroll
        for (int i = 0; i < BM / 32; ++i) {
            int c = i * 4 + wid;
            gload16(Ab + (size_t)(rowTile + c * 8 + lr) * lda + k0 + lc8, &sA[c * 512]);
        }
        #pragma unroll
        for (int i = 0; i < BN / 32; ++i) {
            int c = i * 4 + wid;
            gload16(Bb + (size_t)(colTile + c * 8 + lr) * ldb + k0 + lc8, &sB[c * 512]);
        }
        asm volatile("s_waitcnt vmcnt(0)" ::: "memory");
        __syncthreads();
        #pragma unroll
        for (int kk = 0; kk < 2; ++kk) {
            const int ko = kk * 32 + (lane >> 4) * 8;
            bf16x8 af[MF], bfv[NF];
            #pragma unroll
            for (int m = 0; m < MF; ++m)
                af[m] = *(const bf16x8*)&sA[(wr * (BM / WGM) + m * 16 + (lane & 15)) * 64 + ko];
            #pragma unroll
            for (int n = 0; n < NF; ++n)
                bfv[n] = *(const bf16x8*)&sB[(wc * (BN / WGN) + n * 16 + (lane & 15)) * 64 + ko];
            #pragma unroll
            for (int m = 0; m < MF; ++m)
                #pragma unroll
                for (int n = 0; n < NF; ++n)
                    acc[m][n] = __builtin_amdgcn_mfma_f32_16x16x32_bf16(af[m], bfv[n], acc[m][n], 0, 0, 0);
        }
        __syncthreads();
    }

    const ll offC = zo * offCo + zi * offCi;
    #pragma unroll
    for (int m = 0; m < MF; ++m) {
        #pragma unroll
        for (int n = 0; n < NF; ++n) {
            const int col = colTile + wc * (BN / WGN) + n * 16 + (lane & 15);
            float bv = 0.f;
            if constexpr (BIASK == 1) bv = inp(bias, bias_off + col, md);
            if constexpr (BIASK == 2) bv = ((const float*)bias)[bias_off + col];
            #pragma unroll
            for (int r = 0; r < 4; ++r) {
                const int row = rowTile + wr * (BM / WGM) + m * 16 + ((lane >> 4) << 2) + r;
                float xv = acc[m][n][r] * scale + bv;
                if constexpr (GELU) xv = 0.5f * xv * (1.f + erff(xv * 0.70710678118654752f));
                const size_t idx = (size_t)row * ldc + col;
                if (r1) xv += r1[idx];
                if (r2) xv += r2[idx];
                if constexpr (OUTK == 1)      ((u16*)Cv)[offC + idx] = f2b(xv);
                else if constexpr (OUTK == 0) ((float*)Cv)[offC + idx] = xv;
                else {
                    if (md) ((u16*)Cv)[offC + idx] = f2b(xv);
                    else    ((float*)Cv)[offC + idx] = xv;
                }
            }
        }
    }
}

// ------- transpose input weight (bf16 OR f32) -> bf16 ---------------------------------
__global__ __launch_bounds__(256)
void transpose_k(const void* __restrict__ in, u16* __restrict__ out,
                 int R, int C, int ins, int outs,
                 ll base, ll iStride, ll oStride,
                 const int* __restrict__ modeflag)
{
    __shared__ u16 tile[32][33];
    const int md = *modeflag;
    const int z = blockIdx.z;
    const ll ioff = base + (ll)z * iStride;
    u16* op = out + (ll)z * oStride;
    const int tx = threadIdx.x & 31, ty = threadIdx.x >> 5;
    const int c0 = blockIdx.x * 32, r0 = blockIdx.y * 32;
    #pragma unroll
    for (int i = 0; i < 32; i += 8) {
        int r = r0 + ty + i, c = c0 + tx;
        if (r < R && c < C) tile[ty + i][tx] = f2b(inp(in, ioff + (ll)r * ins + c, md));
    }
    __syncthreads();
    #pragma unroll
    for (int i = 0; i < 32; i += 8) {
        int c = c0 + ty + i, r = r0 + tx;
        if (c < C && r < R) op[(size_t)c * outs + r] = tile[tx][ty + i];
    }
}

// ---- bf16 transpose for internal V slice (qkv cols) ----------------------------------
__global__ __launch_bounds__(256)
void transpose_b_k(const u16* __restrict__ in, u16* __restrict__ out,
                   int R, int C, int ins, int outs,
                   ll iOo, ll iOi, ll oOo, ll oOi, int HB)
{
    __shared__ u16 tile[32][33];
    const int z = blockIdx.z;
    const u16* ip = in  + (ll)(z / HB) * iOo + (ll)(z % HB) * iOi;
    u16*       op = out + (ll)(z / HB) * oOo + (ll)(z % HB) * oOi;
    const int tx = threadIdx.x & 31, ty = threadIdx.x >> 5;
    const int c0 = blockIdx.x * 32, r0 = blockIdx.y * 32;
    #pragma unroll
    for (int i = 0; i < 32; i += 8) {
        int r = r0 + ty + i, c = c0 + tx;
        if (r < R && c < C) tile[ty + i][tx] = ip[(size_t)r * ins + c];
    }
    __syncthreads();
    #pragma unroll
    for (int i = 0; i < 32; i += 8) {
        int c = c0 + ty + i, r = r0 + tx;
        if (c < C && r < R) op[(size_t)c * outs + r] = tile[tx][ty + i];
    }
}

// ---------------- embedding: res = E[x] + P (f32 out) ---------------------------------
__global__ __launch_bounds__(192)
void embed_k(const int* __restrict__ x, const void* __restrict__ E,
             const void* __restrict__ P, float* __restrict__ res,
             const int* __restrict__ modeflag)
{
    const int md = *modeflag;
    const int tok = blockIdx.x, t = threadIdx.x;
    const int s = tok & (cS - 1);
    const ll  eb = (ll)x[tok] * cD, pb = (ll)s * cD;
    float4 o;
    o.x = inp(E, eb + t * 4 + 0, md) + inp(P, pb + t * 4 + 0, md);
    o.y = inp(E, eb + t * 4 + 1, md) + inp(P, pb + t * 4 + 1, md);
    o.z = inp(E, eb + t * 4 + 2, md) + inp(P, pb + t * 4 + 2, md);
    o.w = inp(E, eb + t * 4 + 3, md) + inp(P, pb + t * 4 + 3, md);
    ((float4*)(res + (size_t)tok * cD))[t] = o;
}

// ---------------- layernorm (unbiased std, ddof=1), f32 in, bf16 out ------------------
__global__ __launch_bounds__(192)
void ln_k(const float* __restrict__ in, const void* __restrict__ w,
          const void* __restrict__ b, ll wb_off, u16* __restrict__ out,
          const int* __restrict__ modeflag)
{
    __shared__ float sm[8];
    const int md = *modeflag;
    const int row = blockIdx.x, t = threadIdx.x;
    const float4 x = ((const float4*)(in + (size_t)row * cD))[t];
    float s = wave_sum(x.x + x.y + x.z + x.w);
    const int lane = t & 63, wv = t >> 6;
    if (!lane) sm[wv] = s;
    __syncthreads();
    const float mu = (sm[0] + sm[1] + sm[2]) * (1.f / (float)cD);
    const float dx = x.x - mu, dy = x.y - mu, dz = x.z - mu, dw = x.w - mu;
    float ss = wave_sum(dx * dx + dy * dy + dz * dz + dw * dw);
    if (!lane) sm[4 + wv] = ss;
    __syncthreads();
    const float var = (sm[4] + sm[5] + sm[6]) * (1.f / (float)(cD - 1));
    const float rs  = 1.f / sqrtf(var);
    const ll o4 = wb_off + (ll)t * 4;
    ushort4 o;
    o.x = f2b(inp(w, o4 + 0, md) * (dx * rs) + inp(b, o4 + 0, md));
    o.y = f2b(inp(w, o4 + 1, md) * (dy * rs) + inp(b, o4 + 1, md));
    o.z = f2b(inp(w, o4 + 2, md) * (dz * rs) + inp(b, o4 + 2, md));
    o.w = f2b(inp(w, o4 + 3, md) * (dw * rs) + inp(b, o4 + 3, md));
    ((ushort4*)(out + (size_t)row * cD))[t] = o;
}

// ---------------- causal softmax, in-place on bf16 [rows=BH*S][S] ----------------------
__global__ __launch_bounds__(256)
void softmax_k(u16* __restrict__ p)
{
    __shared__ float sm[8];
    const int row = blockIdx.x;
    const int q = row & (cS - 1);
    u16* pr = p + (size_t)row * cS;
    const int t = threadIdx.x;
    const int j0 = t * 4;
    ushort4 v = {0, 0, 0, 0};
    if (j0 <= q) v = ((const ushort4*)pr)[t];   // skip loads fully in the future
    float x0 = (j0 + 0 <= q) ? b2f(v.x) : -100000.f;
    float x1 = (j0 + 1 <= q) ? b2f(v.y) : -100000.f;
    float x2 = (j0 + 2 <= q) ? b2f(v.z) : -100000.f;
    float x3 = (j0 + 3 <= q) ? b2f(v.w) : -100000.f;
    float mx = wave_max(fmaxf(fmaxf(x0, x1), fmaxf(x2, x3)));
    const int lane = t & 63, wv = t >> 6;
    if (!lane) sm[wv] = mx;
    __syncthreads();
    const float MX = fmaxf(fmaxf(sm[0], sm[1]), fmaxf(sm[2], sm[3]));
    const float e0 = expf(x0 - MX), e1 = expf(x1 - MX), e2 = expf(x2 - MX), e3 = expf(x3 - MX);
    float ssum = wave_sum(e0 + e1 + e2 + e3);
    if (!lane) sm[4 + wv] = ssum;
    __syncthreads();
    const float inv = 1.f / (sm[4] + sm[5] + sm[6] + sm[7]);
    ushort4 o;
    o.x = f2b(e0 * inv); o.y = f2b(e1 * inv); o.z = f2b(e2 * inv); o.w = f2b(e3 * inv);
    ((ushort4*)pr)[t] = o;   // zeros beyond diagonal
}

// =====================================================================================
extern "C" void kernel_launch(void* const* d_in, const int* in_sizes, int n_in,
                              void* d_out, int out_size, void* d_ws, size_t ws_size,
                              hipStream_t stream)
{
    (void)in_sizes; (void)n_in; (void)out_size;
    const int*  x     = (const int*)d_in[0];
    const void* E_w   = d_in[1];
    const void* P_w   = d_in[2];
    const void* ln1_w = d_in[3];
    const void* ln1_b = d_in[4];
    const void* Q_w   = d_in[5];
    const void* Q_b   = d_in[6];
    const void* K_w   = d_in[7];
    const void* K_b   = d_in[8];
    const void* V_w   = d_in[9];
    const void* V_b   = d_in[10];
    const void* O_w   = d_in[11];
    const void* O_b   = d_in[12];
    const void* ln2_w = d_in[13];
    const void* ln2_b = d_in[14];
    const void* In_w  = d_in[15];
    const void* In_b  = d_in[16];
    const void* Out_w = d_in[17];
    const void* Out_b = d_in[18];
    const void* lnf_w = d_in[19];
    const void* lnf_b = d_in[20];
    const void* U_w   = d_in[21];
    const void* U_b   = d_in[22];

    // ---- workspace carve with aliasing (~99 MB) ----
    char* wp = (char*)d_ws;
    auto carve = [&](size_t bytes) { char* r = wp; wp += (bytes + 255) & ~(size_t)255; return r; };
    int*   modeflag = (int*)carve(256);
    float* biasQKV  = (float*)carve((size_t)cL * cQKV * 4);
    float* res   = (float*)carve((size_t)cT * cD * 4);
    float* resat = (float*)carve((size_t)cT * cD * 4);
    u16* h     = (u16*)carve((size_t)cT * cD * 2);
    u16* attnb = (u16*)carve((size_t)cT * cD * 2);
    u16* vt    = (u16*)carve((size_t)cT * cD * 2);
    // qkv [2048][2304] (9.4MB) aliased by mlpb [2048][3072] (12.6MB): lifetimes disjoint
    u16* qkv   = (u16*)carve((size_t)cT * cM * 2);
    u16* mlpb  = qkv;
    u16* WqkvT = (u16*)carve((size_t)cQKV * cD * 2);     // [2304][768]: Q,K,V stacked
    u16* WoT   = (u16*)carve((size_t)cD * cD * 2);
    u16* WinT  = (u16*)carve((size_t)cD * cM * 2);
    u16* WoutT = (u16*)carve((size_t)cD * cM * 2);
    u16* pbuf  = (u16*)carve((size_t)cBH * cS * cS * 2);
    u16* WuT   = pbuf;                                   // alias (pbuf dead after layers)

    if (ws_size && (size_t)(wp - (char*)d_ws) > ws_size) return;  // tripwire

    detect_k<<<1, 64, 0, stream>>>((const uint*)E_w, modeflag);
    packbias_k<<<(cL * cQKV) / 256, 256, 0, stream>>>(Q_b, K_b, V_b, biasQKV, modeflag);
    embed_k<<<cT, 192, 0, stream>>>(x, E_w, P_w, res, modeflag);

    for (int l = 0; l < cL; ++l) {
        const ll wqkv = (ll)l * cH * cD * cDH;
        // per-layer weight transposes (convert f32->bf16 inside)
        transpose_k<<<dim3(2, 24, cH), 256, 0, stream>>>(
            Q_w, WqkvT,                    cD, cDH, cDH, cD, wqkv, (ll)cD * cDH, (ll)cDH * cD, modeflag);
        transpose_k<<<dim3(2, 24, cH), 256, 0, stream>>>(
            K_w, WqkvT + (ll)cD * cD,      cD, cDH, cDH, cD, wqkv, (ll)cD * cDH, (ll)cDH * cD, modeflag);
        transpose_k<<<dim3(2, 24, cH), 256, 0, stream>>>(
            V_w, WqkvT + (ll)2 * cD * cD,  cD, cDH, cDH, cD, wqkv, (ll)cD * cDH, (ll)cDH * cD, modeflag);
        transpose_k<<<dim3(24, 24, 1), 256, 0, stream>>>(
            O_w, WoT, cD, cD, cD, cD, (ll)l * cD * cD, 0, 0, modeflag);
        transpose_k<<<dim3(cM / 32, 24, 1), 256, 0, stream>>>(
            In_w, WinT, cD, cM, cM, cD, (ll)l * cD * cM, 0, 0, modeflag);
        transpose_k<<<dim3(24, cM / 32, 1), 256, 0, stream>>>(
            Out_w, WoutT, cM, cD, cD, cM, (ll)l * cM * cD, 0, 0, modeflag);

        // LN1
        ln_k<<<cT, 192, 0, stream>>>(res, ln1_w, ln1_b, (ll)l * cD, h, modeflag);

        // fused QKV projection: [2048,768] @ [2304,768]^T -> qkv [2048][2304]
        gemm_bt<128, 128, 2, 2, 1, false, true, false, false, 2>
            <<<dim3(cT / 128, cQKV / 128, 1), 256, 0, stream>>>(
            h, cD, 0, 0, WqkvT, cD, 0, 0, qkv, cQKV, 0, 0, 1, cD,
            biasQKV, (ll)l * cQKV, 1.f, nullptr, nullptr, modeflag);

        // V slice -> vt [B,H,DH,S]
        transpose_b_k<<<dim3(2, cS / 32, cBH), 256, 0, stream>>>(
            qkv + 2 * cD, vt, cS, cDH, cQKV, cS,
            (ll)cS * cQKV, cDH, (ll)cH * cDH * cS, (ll)cDH * cS, cH);

        // logits = Q K^T * 1/8, batched over (b,h), causal tile skip
        gemm_bt<128, 128, 2, 2, 1, false, false, true, false, 0>
            <<<dim3(8, 8, cBH), 256, 0, stream>>>(
            qkv, cQKV, (ll)cS * cQKV, cDH,
            qkv + cD, cQKV, (ll)cS * cQKV, cDH,
            pbuf, cS, (ll)cH * cS * cS, (ll)cS * cS,
            cH, cDH, nullptr, 0, 0.125f, nullptr, nullptr, modeflag);

        softmax_k<<<cBH * cS, 256, 0, stream>>>(pbuf);

        // attn = P V, batched, causal K-limit
        gemm_bt<128, 64, 4, 1, 1, false, false, false, true, 0>
            <<<dim3(1, 8, cBH), 256, 0, stream>>>(
            pbuf, cS, (ll)cH * cS * cS, (ll)cS * cS,
            vt, cS, (ll)cH * cDH * cS, (ll)cDH * cS,
            attnb, cD, (ll)cS * cD, cDH,
            cH, cS, nullptr, 0, 1.f, nullptr, nullptr, modeflag);

        // O projection + residual -> resat (f32)
        gemm_bt<128, 128, 2, 2, 0, false, true, false, false, 1>
            <<<dim3(cT / 128, cD / 128, 1), 256, 0, stream>>>(
            attnb, cD, 0, 0, WoT, cD, 0, 0, resat, cD, 0, 0, 1, cD,
            O_b, (ll)l * cD, 1.f, res, nullptr, modeflag);

        // LN2
        ln_k<<<cT, 192, 0, stream>>>(resat, ln2_w, ln2_b, (ll)l * cD, h, modeflag);

        // MLP in: gelu(h @ Win + bIn)
        gemm_bt<128, 128, 2, 2, 1, true, true, false, false, 1>
            <<<dim3(cT / 128, cM / 128, 1), 256, 0, stream>>>(
            h, cD, 0, 0, WinT, cD, 0, 0, mlpb, cM, 0, 0, 1, cD,
            In_b, (ll)l * cM, 1.f, nullptr, nullptr, modeflag);

        // MLP out + double residual: res = res + resat + (m @ Wout + bOut)
        gemm_bt<128, 128, 2, 2, 0, false, true, false, false, 1>
            <<<dim3(cT / 128, cD / 128, 1), 256, 0, stream>>>(
            mlpb, cM, 0, 0, WoutT, cM, 0, 0, res, cD, 0, 0, 1, cM,
            Out_b, (ll)l * cD, 1.f, res, resat, modeflag);
    }

    // unembed weight transpose (WuT aliases pbuf), final LN, unembed
    transpose_k<<<dim3(cV / 32, cD / 32, 1), 256, 0, stream>>>(
        U_w, WuT, cD, cV, cV, cD, 0, 0, 0, modeflag);
    ln_k<<<cT, 192, 0, stream>>>(res, lnf_w, lnf_b, 0, h, modeflag);
    gemm_bt<128, 128, 2, 2, 2, false, true, false, false, 1>
        <<<dim3(cT / 128, cV / 128, 1), 256, 0, stream>>>(
        h, cD, 0, 0, WuT, cD, 0, 0, d_out, cV, 0, 0, 1, cD,
        U_b, 0, 1.f, nullptr, nullptr, modeflag);
}